// Round 2
// baseline (1502.438 us; speedup 1.0000x reference)
//
#include <hip/hip_runtime.h>
#include <math.h>

#define K_IN 12288
#define HID  1024
#define G4   4096
#define TS   256

typedef unsigned long long u64;
typedef unsigned int u32;

// ---------------------------------------------------------------------------
// Kernel 1: partial GEMM  xpart[ks][t][j] = dot(x[t, kspan], W_ih[j, kspan])
// fp32 vector GEMM, 128(j) x 128(t) x BK=16 tile, 8x8 micro-tile per thread
// (2x2 strips of 4 so LDS reads are at 4-float stride = 2-way conflict, free).
// Next-tile global loads are prefetched into registers before the inner loop
// so HBM latency hides under the 16-kk compute. K split across blockIdx.z.
// ---------------------------------------------------------------------------
#define GBM 128   // j per block
#define GBN 128   // t per block
#define GBK 16
#define LDG 132   // padded LDS row stride (floats); 132*4B = 16B-aligned rows

#define MAC44(ACC, A, B)                                                     \
  ACC[0][0] += A.x * B.x; ACC[0][1] += A.x * B.y;                            \
  ACC[0][2] += A.x * B.z; ACC[0][3] += A.x * B.w;                            \
  ACC[1][0] += A.y * B.x; ACC[1][1] += A.y * B.y;                            \
  ACC[1][2] += A.y * B.z; ACC[1][3] += A.y * B.w;                            \
  ACC[2][0] += A.z * B.x; ACC[2][1] += A.z * B.y;                            \
  ACC[2][2] += A.z * B.z; ACC[2][3] += A.z * B.w;                            \
  ACC[3][0] += A.w * B.x; ACC[3][1] += A.w * B.y;                            \
  ACC[3][2] += A.w * B.z; ACC[3][3] += A.w * B.w;

__global__ __launch_bounds__(256, 2) void xproj_gemm(
    const float* __restrict__ X,    // (256, 12288)
    const float* __restrict__ W,    // (4096, 12288)
    float* __restrict__ xpart,      // (nks, 256, 4096)
    int kspan)
{
  __shared__ float As[GBK][LDG];  // k-major: As[k][j-local]
  __shared__ float Bs[GBK][LDG];  // k-major: Bs[k][t-local]
  const int tid = threadIdx.x;
  const int t0 = blockIdx.x * GBN;
  const int j0 = blockIdx.y * GBM;
  const int ks = blockIdx.z;
  const int kbeg = ks * kspan;
  const int kend = kbeg + kspan;

  // compute mapping: 16 x 16 threads, each owns {ca0..+3, ca1..+3} x {cb0.., cb1..}
  const int tx = tid & 15;
  const int ty = tid >> 4;
  const int ca0 = tx * 4, ca1 = 64 + tx * 4;
  const int cb0 = ty * 4, cb1 = 64 + ty * 4;

  // staging mapping: rows r0 and 64+r0, k-quad kq
  const int r0 = tid >> 2;   // 0..63
  const int kq = tid & 3;

  float acc[2][2][4][4];
#pragma unroll
  for (int ia = 0; ia < 2; ++ia)
#pragma unroll
    for (int ib = 0; ib < 2; ++ib)
#pragma unroll
      for (int a = 0; a < 4; ++a)
#pragma unroll
        for (int b = 0; b < 4; ++b) acc[ia][ib][a][b] = 0.f;

  // prologue: load first K-tile into registers
  float4 a0v = *(const float4*)(W + (size_t)(j0 + r0) * K_IN + kbeg + kq * 4);
  float4 a1v = *(const float4*)(W + (size_t)(j0 + 64 + r0) * K_IN + kbeg + kq * 4);
  float4 b0v = *(const float4*)(X + (size_t)(t0 + r0) * K_IN + kbeg + kq * 4);
  float4 b1v = *(const float4*)(X + (size_t)(t0 + 64 + r0) * K_IN + kbeg + kq * 4);

  for (int k0 = kbeg; k0 < kend; k0 += GBK) {
    __syncthreads();  // previous inner loop done reading LDS
    As[kq * 4 + 0][r0] = a0v.x; As[kq * 4 + 1][r0] = a0v.y;
    As[kq * 4 + 2][r0] = a0v.z; As[kq * 4 + 3][r0] = a0v.w;
    As[kq * 4 + 0][64 + r0] = a1v.x; As[kq * 4 + 1][64 + r0] = a1v.y;
    As[kq * 4 + 2][64 + r0] = a1v.z; As[kq * 4 + 3][64 + r0] = a1v.w;
    Bs[kq * 4 + 0][r0] = b0v.x; Bs[kq * 4 + 1][r0] = b0v.y;
    Bs[kq * 4 + 2][r0] = b0v.z; Bs[kq * 4 + 3][r0] = b0v.w;
    Bs[kq * 4 + 0][64 + r0] = b1v.x; Bs[kq * 4 + 1][64 + r0] = b1v.y;
    Bs[kq * 4 + 2][64 + r0] = b1v.z; Bs[kq * 4 + 3][64 + r0] = b1v.w;
    __syncthreads();

    // prefetch next K-tile (latency hides under the 16-kk compute below)
    const int kn = k0 + GBK;
    if (kn < kend) {
      a0v = *(const float4*)(W + (size_t)(j0 + r0) * K_IN + kn + kq * 4);
      a1v = *(const float4*)(W + (size_t)(j0 + 64 + r0) * K_IN + kn + kq * 4);
      b0v = *(const float4*)(X + (size_t)(t0 + r0) * K_IN + kn + kq * 4);
      b1v = *(const float4*)(X + (size_t)(t0 + 64 + r0) * K_IN + kn + kq * 4);
    }

#pragma unroll
    for (int kk = 0; kk < GBK; ++kk) {
      float4 a0 = *(const float4*)&As[kk][ca0];
      float4 a1 = *(const float4*)&As[kk][ca1];
      float4 b0 = *(const float4*)&Bs[kk][cb0];
      float4 b1 = *(const float4*)&Bs[kk][cb1];
      MAC44(acc[0][0], a0, b0);
      MAC44(acc[0][1], a0, b1);
      MAC44(acc[1][0], a1, b0);
      MAC44(acc[1][1], a1, b1);
    }
  }

  float* outp = xpart + (size_t)ks * TS * G4;
#pragma unroll
  for (int ib = 0; ib < 2; ++ib) {
    const int tb = t0 + (ib ? cb1 : cb0);
#pragma unroll
    for (int y = 0; y < 4; ++y) {
#pragma unroll
      for (int ia = 0; ia < 2; ++ia) {
        float4 o;
        o.x = acc[ia][ib][0][y]; o.y = acc[ia][ib][1][y];
        o.z = acc[ia][ib][2][y]; o.w = acc[ia][ib][3][y];
        *(float4*)(outp + (size_t)(tb + y) * G4 + j0 + (ia ? ca1 : ca0)) = o;
      }
    }
  }
}

// ---------------------------------------------------------------------------
// Kernel 1b: xproj[t][j] = sum_ks xpart[ks][t][j] + b_ih[j] + b_hh[j]
// ---------------------------------------------------------------------------
__global__ __launch_bounds__(256) void xproj_reduce(
    const float* __restrict__ xpart, int nks,
    const float* __restrict__ b_ih, const float* __restrict__ b_hh,
    float* __restrict__ xproj)
{
  const int idx = (blockIdx.x * 256 + threadIdx.x) * 4;  // over TS*G4 elems
  float4 s = *(const float4*)(xpart + idx);
  for (int ks = 1; ks < nks; ++ks) {
    float4 p = *(const float4*)(xpart + (size_t)ks * TS * G4 + idx);
    s.x += p.x; s.y += p.y; s.z += p.z; s.w += p.w;
  }
  const int j = idx & (G4 - 1);
  float4 bi = *(const float4*)(b_ih + j);
  float4 bh = *(const float4*)(b_hh + j);
  s.x += bi.x + bh.x; s.y += bi.y + bh.y; s.z += bi.z + bh.z; s.w += bi.w + bh.w;
  *(float4*)(xproj + idx) = s;
}

// ---------------------------------------------------------------------------
// Kernel 2: persistent LSTM scan. 128 WGs x 256 threads.
// Row mapping: r = tid>>3 (0..31), gate = r&3, unit = r>>2  -> a unit's 4
// gates live in one half-wave, so gate exchange is 4 __shfl (no LDS, no
// barrier) and cell state c lives replicated in registers per half-wave.
// Receive: poll ALL 4 h-slots with independent relaxed 8B atomic loads per
// iteration (the old per-slot do-while serialized 4 coherence round trips —
// that was the dominant per-step cost). h_lds is double-buffered so a single
// __syncthreads per step (write->read) suffices; the buffer reused at t+2 is
// protected by the barrier at t+1 (all threads' t-step reads precede it).
// Slot overwrite safety: every WG reads every slot each step, so tag t -> t+2
// overwrite can only happen after all WGs consumed tag t (same invariant as
// before, also covers stale tags left over from a previous bench iteration).
// ---------------------------------------------------------------------------
#define NWG 128
#define UPW 8

__global__ __launch_bounds__(256, 1) void lstm_scan(
    const float* __restrict__ W_hh,   // (4096, 1024)
    const float* __restrict__ xproj,  // (256, 4096)
    u64* __restrict__ hmsg)           // (2, 1024) packed {tag,val}
{
  const int tid = threadIdx.x;
  const int w = blockIdx.x;
  const int u0 = w * UPW;
  const int r = tid >> 3;            // 0..31 local row
  const int sub = tid & 7;           // 8 lanes per row, 128 h-elems each
  const int gate = r & 3;            // 0..3  (i,f,g,o)
  const int hrow = gate * HID + u0 + (r >> 2);
  const int lane = tid & 63;

  __shared__ __align__(16) float h_lds[2][8 * 132];

  // my 128-float W_hh segment in registers (read once per step)
  float4 Wreg[32];
  const float4* wp = (const float4*)(W_hh + (size_t)hrow * HID + sub * 128);
#pragma unroll
  for (int i = 0; i < 32; ++i) Wreg[i] = wp[i];

  float c_reg = 0.f;  // valid (and identical) across each half-wave

  for (int t = 0; t < TS; ++t) {
    // prefetch my xproj element early (hides L2/L3 latency behind the spin)
    float xp = xproj[(size_t)t * G4 + hrow];

    float p0 = 0.f, p1 = 0.f, p2 = 0.f, p3 = 0.f;
    if (t > 0) {
      const u64* slot = hmsg + (t & 1) * HID;
      const u32 tt = (u32)t;
      u64 m0, m1, m2, m3;
      for (;;) {
        m0 = __hip_atomic_load(&slot[tid * 4 + 0], __ATOMIC_RELAXED,
                               __HIP_MEMORY_SCOPE_AGENT);
        m1 = __hip_atomic_load(&slot[tid * 4 + 1], __ATOMIC_RELAXED,
                               __HIP_MEMORY_SCOPE_AGENT);
        m2 = __hip_atomic_load(&slot[tid * 4 + 2], __ATOMIC_RELAXED,
                               __HIP_MEMORY_SCOPE_AGENT);
        m3 = __hip_atomic_load(&slot[tid * 4 + 3], __ATOMIC_RELAXED,
                               __HIP_MEMORY_SCOPE_AGENT);
        if (((u32)(m0 >> 32) == tt) & ((u32)(m1 >> 32) == tt) &
            ((u32)(m2 >> 32) == tt) & ((u32)(m3 >> 32) == tt))
          break;
      }
      float* hb = h_lds[t & 1];
      const int st = tid >> 5;
      const int off = (tid & 31) * 4;
      hb[st * 132 + off + 0] = __uint_as_float((u32)m0);
      hb[st * 132 + off + 1] = __uint_as_float((u32)m1);
      hb[st * 132 + off + 2] = __uint_as_float((u32)m2);
      hb[st * 132 + off + 3] = __uint_as_float((u32)m3);
      __syncthreads();  // h_lds[t&1] ready
      const float4* hl = (const float4*)(hb + sub * 132);
#pragma unroll
      for (int i = 0; i < 32; i += 4) {
        float4 h4;
        h4 = hl[i + 0];
        p0 += Wreg[i + 0].x * h4.x + Wreg[i + 0].y * h4.y +
              Wreg[i + 0].z * h4.z + Wreg[i + 0].w * h4.w;
        h4 = hl[i + 1];
        p1 += Wreg[i + 1].x * h4.x + Wreg[i + 1].y * h4.y +
              Wreg[i + 1].z * h4.z + Wreg[i + 1].w * h4.w;
        h4 = hl[i + 2];
        p2 += Wreg[i + 2].x * h4.x + Wreg[i + 2].y * h4.y +
              Wreg[i + 2].z * h4.z + Wreg[i + 2].w * h4.w;
        h4 = hl[i + 3];
        p3 += Wreg[i + 3].x * h4.x + Wreg[i + 3].y * h4.y +
              Wreg[i + 3].z * h4.z + Wreg[i + 3].w * h4.w;
      }
    }
    float partial = (p0 + p1) + (p2 + p3);
    // reduce across the 8 sub-lanes of this row (same wave)
    partial += __shfl_xor(partial, 1, 64);
    partial += __shfl_xor(partial, 2, 64);
    partial += __shfl_xor(partial, 4, 64);
    float gsum = partial + xp;
    float act = (gate == 2) ? tanhf(gsum) : 1.f / (1.f + expf(-gsum));
    // gather this half-wave's unit gates: rows base/8.. hold i,f,g,o
    const int base = lane & 32;
    float iv = __shfl(act, base + 0, 64);
    float fv = __shfl(act, base + 8, 64);
    float gv = __shfl(act, base + 16, 64);
    float ov = __shfl(act, base + 24, 64);
    c_reg = fv * c_reg + iv * gv;
    float hnew = ov * tanhf(c_reg);
    if ((lane & 31) == 0) {
      u64 msg = ((u64)(u32)(t + 1) << 32) | (u64)__float_as_uint(hnew);
      __hip_atomic_store(&hmsg[((t + 1) & 1) * HID + u0 + (tid >> 5)], msg,
                         __ATOMIC_RELAXED, __HIP_MEMORY_SCOPE_AGENT);
    }
    // no trailing barrier: next step's barrier protects LDS buffer reuse
  }
}

// ---------------------------------------------------------------------------
// Kernel 3: out[j] = dot(fc_w[j,:], h_T) + fc_b[j].  h_T packed in hmsg slot 0
// (tag 256, step 256 is even) — extract low 32 bits.
// ---------------------------------------------------------------------------
__global__ __launch_bounds__(256) void fc_kernel(
    const float* __restrict__ fc_w,  // (12288, 1024)
    const float* __restrict__ fc_b,  // (12288)
    const u64* __restrict__ hmsg,    // h_T packed at slot 0
    float* __restrict__ out)         // (12288)
{
  __shared__ float h_s[HID];
  const int tid = threadIdx.x;
  for (int k = tid; k < HID; k += 256)
    h_s[k] = __uint_as_float((u32)hmsg[k]);
  __syncthreads();
  const int r = tid >> 2;    // 0..63
  const int sub = tid & 3;   // 256 elems each
  const int j = blockIdx.x * 64 + r;
  const float4* wrow = (const float4*)(fc_w + (size_t)j * HID + sub * 256);
  const float4* hp = (const float4*)(h_s + sub * 256);
  float s = 0.f;
#pragma unroll
  for (int i = 0; i < 64; ++i) {
    float4 wv = wrow[i];
    float4 hv = hp[i];
    s += wv.x * hv.x + wv.y * hv.y + wv.z * hv.z + wv.w * hv.w;
  }
  s += __shfl_xor(s, 1, 64);
  s += __shfl_xor(s, 2, 64);
  if (sub == 0) out[j] = s + fc_b[j];
}

// ---------------------------------------------------------------------------
extern "C" void kernel_launch(void* const* d_in, const int* in_sizes, int n_in,
                              void* d_out, int out_size, void* d_ws, size_t ws_size,
                              hipStream_t stream) {
  const float* frames = (const float*)d_in[0];  // (256,3,64,64)
  const float* W_ih   = (const float*)d_in[1];  // (4096,12288)
  const float* W_hh   = (const float*)d_in[2];  // (4096,1024)
  const float* b_ih   = (const float*)d_in[3];  // (4096)
  const float* b_hh   = (const float*)d_in[4];  // (4096)
  const float* fc_w   = (const float*)d_in[5];  // (12288,1024)
  const float* fc_b   = (const float*)d_in[6];  // (12288)
  float* out = (float*)d_out;

  const size_t XPROJ_BYTES = (size_t)TS * G4 * 4;  // 4 MB
  // pick K-split by available workspace (ws_size is constant across calls).
  // 128x128 tiles -> 64 tiles; need nks>=4 for >=1 block/CU, prefer 8 (2/CU).
  int nks = 1;
  if (ws_size >= XPROJ_BYTES * 9 + (1 << 20)) nks = 8;
  else if (ws_size >= XPROJ_BYTES * 5 + (1 << 20)) nks = 4;
  else if (ws_size >= XPROJ_BYTES * 3 + (1 << 20)) nks = 2;

  char* ws = (char*)d_ws;
  float* xproj = (float*)ws;                                  // 4 MB
  float* xpart = (float*)(ws + XPROJ_BYTES);                  // nks * 4 MB
  u64*   hmsg  = (u64*)(ws + XPROJ_BYTES * (1 + nks));        // 16 KB
  // hmsg deliberately NOT initialized: 0xAA poison tag never matches [1,256].

  const int kspan = K_IN / nks;
  xproj_gemm<<<dim3(TS / GBN, G4 / GBM, nks), 256, 0, stream>>>(frames, W_ih, xpart, kspan);
  xproj_reduce<<<dim3(TS * G4 / 4 / 256), 256, 0, stream>>>(xpart, nks, b_ih, b_hh, xproj);
  lstm_scan<<<dim3(NWG), 256, 0, stream>>>(W_hh, xproj, hmsg);
  fc_kernel<<<dim3(12288 / 64), 256, 0, stream>>>(fc_w, fc_b, hmsg, out);
}

// Round 4
// 1209.139 us; speedup vs baseline: 1.2426x; 1.2426x over previous
//
#include <hip/hip_runtime.h>
#include <math.h>

#define K_IN 12288
#define HID  1024
#define G4   4096
#define TS   256

typedef unsigned long long u64;
typedef unsigned int u32;

// ---------------------------------------------------------------------------
// Kernel 1: partial GEMM  xpart[ks][t][j] = dot(x[t, kspan], W_ih[j, kspan])
// fp32 vector GEMM, 128(j) x 128(t) x BK=16 tile, 8x8 micro-tile per thread.
// ---------------------------------------------------------------------------
#define GBM 128   // j per block
#define GBN 128   // t per block
#define GBK 16
#define LDG 132   // padded LDS row stride (floats)

#define MAC44(ACC, A, B)                                                     \
  ACC[0][0] += A.x * B.x; ACC[0][1] += A.x * B.y;                            \
  ACC[0][2] += A.x * B.z; ACC[0][3] += A.x * B.w;                            \
  ACC[1][0] += A.y * B.x; ACC[1][1] += A.y * B.y;                            \
  ACC[1][2] += A.y * B.z; ACC[1][3] += A.y * B.w;                            \
  ACC[2][0] += A.z * B.x; ACC[2][1] += A.z * B.y;                            \
  ACC[2][2] += A.z * B.z; ACC[2][3] += A.z * B.w;                            \
  ACC[3][0] += A.w * B.x; ACC[3][1] += A.w * B.y;                            \
  ACC[3][2] += A.w * B.z; ACC[3][3] += A.w * B.w;

__global__ __launch_bounds__(256, 2) void xproj_gemm(
    const float* __restrict__ X,    // (256, 12288)
    const float* __restrict__ W,    // (4096, 12288)
    float* __restrict__ xpart,      // (nks, 256, 4096)
    int kspan)
{
  __shared__ float As[GBK][LDG];  // k-major: As[k][j-local]
  __shared__ float Bs[GBK][LDG];  // k-major: Bs[k][t-local]
  const int tid = threadIdx.x;
  const int t0 = blockIdx.x * GBN;
  const int j0 = blockIdx.y * GBM;
  const int ks = blockIdx.z;
  const int kbeg = ks * kspan;
  const int kend = kbeg + kspan;

  const int tx = tid & 15;
  const int ty = tid >> 4;
  const int ca0 = tx * 4, ca1 = 64 + tx * 4;
  const int cb0 = ty * 4, cb1 = 64 + ty * 4;

  const int r0 = tid >> 2;   // 0..63
  const int kq = tid & 3;

  float acc[2][2][4][4];
#pragma unroll
  for (int ia = 0; ia < 2; ++ia)
#pragma unroll
    for (int ib = 0; ib < 2; ++ib)
#pragma unroll
      for (int a = 0; a < 4; ++a)
#pragma unroll
        for (int b = 0; b < 4; ++b) acc[ia][ib][a][b] = 0.f;

  float4 a0v = *(const float4*)(W + (size_t)(j0 + r0) * K_IN + kbeg + kq * 4);
  float4 a1v = *(const float4*)(W + (size_t)(j0 + 64 + r0) * K_IN + kbeg + kq * 4);
  float4 b0v = *(const float4*)(X + (size_t)(t0 + r0) * K_IN + kbeg + kq * 4);
  float4 b1v = *(const float4*)(X + (size_t)(t0 + 64 + r0) * K_IN + kbeg + kq * 4);

  for (int k0 = kbeg; k0 < kend; k0 += GBK) {
    __syncthreads();
    As[kq * 4 + 0][r0] = a0v.x; As[kq * 4 + 1][r0] = a0v.y;
    As[kq * 4 + 2][r0] = a0v.z; As[kq * 4 + 3][r0] = a0v.w;
    As[kq * 4 + 0][64 + r0] = a1v.x; As[kq * 4 + 1][64 + r0] = a1v.y;
    As[kq * 4 + 2][64 + r0] = a1v.z; As[kq * 4 + 3][64 + r0] = a1v.w;
    Bs[kq * 4 + 0][r0] = b0v.x; Bs[kq * 4 + 1][r0] = b0v.y;
    Bs[kq * 4 + 2][r0] = b0v.z; Bs[kq * 4 + 3][r0] = b0v.w;
    Bs[kq * 4 + 0][64 + r0] = b1v.x; Bs[kq * 4 + 1][64 + r0] = b1v.y;
    Bs[kq * 4 + 2][64 + r0] = b1v.z; Bs[kq * 4 + 3][64 + r0] = b1v.w;
    __syncthreads();

    const int kn = k0 + GBK;
    if (kn < kend) {
      a0v = *(const float4*)(W + (size_t)(j0 + r0) * K_IN + kn + kq * 4);
      a1v = *(const float4*)(W + (size_t)(j0 + 64 + r0) * K_IN + kn + kq * 4);
      b0v = *(const float4*)(X + (size_t)(t0 + r0) * K_IN + kn + kq * 4);
      b1v = *(const float4*)(X + (size_t)(t0 + 64 + r0) * K_IN + kn + kq * 4);
    }

#pragma unroll
    for (int kk = 0; kk < GBK; ++kk) {
      float4 a0 = *(const float4*)&As[kk][ca0];
      float4 a1 = *(const float4*)&As[kk][ca1];
      float4 b0 = *(const float4*)&Bs[kk][cb0];
      float4 b1 = *(const float4*)&Bs[kk][cb1];
      MAC44(acc[0][0], a0, b0);
      MAC44(acc[0][1], a0, b1);
      MAC44(acc[1][0], a1, b0);
      MAC44(acc[1][1], a1, b1);
    }
  }

  float* outp = xpart + (size_t)ks * TS * G4;
#pragma unroll
  for (int ib = 0; ib < 2; ++ib) {
    const int tb = t0 + (ib ? cb1 : cb0);
#pragma unroll
    for (int y = 0; y < 4; ++y) {
#pragma unroll
      for (int ia = 0; ia < 2; ++ia) {
        float4 o;
        o.x = acc[ia][ib][0][y]; o.y = acc[ia][ib][1][y];
        o.z = acc[ia][ib][2][y]; o.w = acc[ia][ib][3][y];
        *(float4*)(outp + (size_t)(tb + y) * G4 + j0 + (ia ? ca1 : ca0)) = o;
      }
    }
  }
}

// ---------------------------------------------------------------------------
// Kernel 1b: xproj[t][j] = sum_ks xpart[ks][t][j] + b_ih[j] + b_hh[j]
// ---------------------------------------------------------------------------
__global__ __launch_bounds__(256) void xproj_reduce(
    const float* __restrict__ xpart, int nks,
    const float* __restrict__ b_ih, const float* __restrict__ b_hh,
    float* __restrict__ xproj)
{
  const int idx = (blockIdx.x * 256 + threadIdx.x) * 4;
  float4 s = *(const float4*)(xpart + idx);
  for (int ks = 1; ks < nks; ++ks) {
    float4 p = *(const float4*)(xpart + (size_t)ks * TS * G4 + idx);
    s.x += p.x; s.y += p.y; s.z += p.z; s.w += p.w;
  }
  const int j = idx & (G4 - 1);
  float4 bi = *(const float4*)(b_ih + j);
  float4 bh = *(const float4*)(b_hh + j);
  s.x += bi.x + bh.x; s.y += bi.y + bh.y; s.z += bi.z + bh.z; s.w += bi.w + bh.w;
  *(float4*)(xproj + idx) = s;
}

// ---------------------------------------------------------------------------
// Kernel 2: persistent LSTM scan — EXACT round-0 structure (proven 687 µs)
// with ONE change in the receive path:
//   Old: 4 serialized do-while spins (3 dependent coherence round-trips after
//        slot 0 matched — ~0.9 µs/step of pure serial latency).
//   New: spin on slot 0 only (same steady-state poll rate as the proven
//        version: 1 load/thread/iter — the round-1 4-wide poll congested the
//        fabric, 687→938 µs). Once slot 0 carries tag t, slots 1-3 are
//        batch-loaded in parallel; they were published by the SAME wave64
//        store instruction as slot 0 (producer = threads 0-7 of wave 0), so
//        the verify loops pass on the first check in the common case.
// Everything else (B1/B2/B3 barriers, gates_lds, c_lds, sub==0 xp load,
// producer tid<8) is byte-identical to the 687 µs version.
// ---------------------------------------------------------------------------
#define NWG 128
#define UPW 8

__global__ __launch_bounds__(256, 1) void lstm_scan(
    const float* __restrict__ W_hh,   // (4096, 1024)
    const float* __restrict__ xproj,  // (256, 4096)
    u64* __restrict__ hmsg)           // (2, 1024) packed {tag,val}
{
  const int tid = threadIdx.x;
  const int w = blockIdx.x;
  const int u0 = w * UPW;
  const int r = tid >> 3;            // 0..31 local row
  const int sub = tid & 7;           // 8 lanes per row, 128 elems each
  const int gate = r >> 3;           // 0..3
  const int uu = r & 7;              // 0..7
  const int hrow = gate * HID + u0 + uu;

  __shared__ __align__(16) float h_lds[8 * 132];
  __shared__ float gates_lds[32];
  __shared__ float c_lds[UPW];

  // my 128-float W_hh segment in registers
  float4 Wreg[32];
  const float4* wp = (const float4*)(W_hh + (size_t)hrow * HID + sub * 128);
#pragma unroll
  for (int i = 0; i < 32; ++i) Wreg[i] = wp[i];

  if (tid < UPW) c_lds[tid] = 0.f;
  __syncthreads();

  for (int t = 0; t < TS; ++t) {
    // prefetch my xproj element early (hides L2/L3 latency behind the spin)
    float xp = 0.f;
    if (sub == 0) xp = xproj[(size_t)t * G4 + hrow];

    float partial = 0.f;
    if (t > 0) {
      const u64* slot = hmsg + (t & 1) * HID;
      const u32 tt = (u32)t;
      u64 m0, m1, m2, m3;
      // spin on slot 0 only (1 load/thread/iter — proven-safe poll rate)
      do {
        m0 = __hip_atomic_load(&slot[tid * 4 + 0], __ATOMIC_RELAXED,
                               __HIP_MEMORY_SCOPE_AGENT);
      } while ((u32)(m0 >> 32) != tt);
      // slots 1-3: batch issue (independent loads -> one round-trip), verify
      m1 = __hip_atomic_load(&slot[tid * 4 + 1], __ATOMIC_RELAXED,
                             __HIP_MEMORY_SCOPE_AGENT);
      m2 = __hip_atomic_load(&slot[tid * 4 + 2], __ATOMIC_RELAXED,
                             __HIP_MEMORY_SCOPE_AGENT);
      m3 = __hip_atomic_load(&slot[tid * 4 + 3], __ATOMIC_RELAXED,
                             __HIP_MEMORY_SCOPE_AGENT);
      while ((u32)(m1 >> 32) != tt)
        m1 = __hip_atomic_load(&slot[tid * 4 + 1], __ATOMIC_RELAXED,
                               __HIP_MEMORY_SCOPE_AGENT);
      while ((u32)(m2 >> 32) != tt)
        m2 = __hip_atomic_load(&slot[tid * 4 + 2], __ATOMIC_RELAXED,
                               __HIP_MEMORY_SCOPE_AGENT);
      while ((u32)(m3 >> 32) != tt)
        m3 = __hip_atomic_load(&slot[tid * 4 + 3], __ATOMIC_RELAXED,
                               __HIP_MEMORY_SCOPE_AGENT);
      __syncthreads();  // B1: prev step's h_lds readers done
      const int st = tid >> 5;
      const int off = (tid & 31) * 4;
      h_lds[st * 132 + off + 0] = __uint_as_float((u32)m0);
      h_lds[st * 132 + off + 1] = __uint_as_float((u32)m1);
      h_lds[st * 132 + off + 2] = __uint_as_float((u32)m2);
      h_lds[st * 132 + off + 3] = __uint_as_float((u32)m3);
      __syncthreads();  // B2: h_lds ready
      const float4* hl = (const float4*)(h_lds + sub * 132);
#pragma unroll
      for (int i = 0; i < 32; ++i) {
        float4 h4 = hl[i];
        partial += Wreg[i].x * h4.x + Wreg[i].y * h4.y +
                   Wreg[i].z * h4.z + Wreg[i].w * h4.w;
      }
    }
    // reduce across the 8 sub-lanes of this row (same wave)
    partial += __shfl_xor(partial, 1, 64);
    partial += __shfl_xor(partial, 2, 64);
    partial += __shfl_xor(partial, 4, 64);
    if (sub == 0) {
      float gsum = partial + xp;
      float act = (gate == 2) ? tanhf(gsum) : 1.f / (1.f + expf(-gsum));
      gates_lds[gate * 8 + uu] = act;
    }
    __syncthreads();  // B3: gates ready
    if (tid < UPW) {
      float iv = gates_lds[0 * 8 + tid];
      float fv = gates_lds[1 * 8 + tid];
      float gv = gates_lds[2 * 8 + tid];
      float ov = gates_lds[3 * 8 + tid];
      float c = fv * c_lds[tid] + iv * gv;
      c_lds[tid] = c;
      float hnew = ov * tanhf(c);
      u64 msg = ((u64)(u32)(t + 1) << 32) | (u64)__float_as_uint(hnew);
      __hip_atomic_store(&hmsg[((t + 1) & 1) * HID + u0 + tid], msg,
                         __ATOMIC_RELAXED, __HIP_MEMORY_SCOPE_AGENT);
    }
    // no trailing barrier needed: B1/B3 of the next iteration protect LDS
  }
}

// ---------------------------------------------------------------------------
// Kernel 3: out[j] = dot(fc_w[j,:], h_T) + fc_b[j].
// ---------------------------------------------------------------------------
__global__ __launch_bounds__(256) void fc_kernel(
    const float* __restrict__ fc_w,  // (12288, 1024)
    const float* __restrict__ fc_b,  // (12288)
    const u64* __restrict__ hmsg,    // h_T packed at slot 0
    float* __restrict__ out)         // (12288)
{
  __shared__ float h_s[HID];
  const int tid = threadIdx.x;
  for (int k = tid; k < HID; k += 256)
    h_s[k] = __uint_as_float((u32)hmsg[k]);
  __syncthreads();
  const int r = tid >> 2;    // 0..63
  const int sub = tid & 3;   // 256 elems each
  const int j = blockIdx.x * 64 + r;
  const float4* wrow = (const float4*)(fc_w + (size_t)j * HID + sub * 256);
  const float4* hp = (const float4*)(h_s + sub * 256);
  float s = 0.f;
#pragma unroll
  for (int i = 0; i < 64; ++i) {
    float4 wv = wrow[i];
    float4 hv = hp[i];
    s += wv.x * hv.x + wv.y * hv.y + wv.z * hv.z + wv.w * hv.w;
  }
  s += __shfl_xor(s, 1, 64);
  s += __shfl_xor(s, 2, 64);
  if (sub == 0) out[j] = s + fc_b[j];
}

// ---------------------------------------------------------------------------
extern "C" void kernel_launch(void* const* d_in, const int* in_sizes, int n_in,
                              void* d_out, int out_size, void* d_ws, size_t ws_size,
                              hipStream_t stream) {
  const float* frames = (const float*)d_in[0];  // (256,3,64,64)
  const float* W_ih   = (const float*)d_in[1];  // (4096,12288)
  const float* W_hh   = (const float*)d_in[2];  // (4096,1024)
  const float* b_ih   = (const float*)d_in[3];  // (4096)
  const float* b_hh   = (const float*)d_in[4];  // (4096)
  const float* fc_w   = (const float*)d_in[5];  // (12288,1024)
  const float* fc_b   = (const float*)d_in[6];  // (12288)
  float* out = (float*)d_out;

  const size_t XPROJ_BYTES = (size_t)TS * G4 * 4;  // 4 MB
  int nks = 1;
  if (ws_size >= XPROJ_BYTES * 9 + (1 << 20)) nks = 8;
  else if (ws_size >= XPROJ_BYTES * 5 + (1 << 20)) nks = 4;
  else if (ws_size >= XPROJ_BYTES * 3 + (1 << 20)) nks = 2;

  char* ws = (char*)d_ws;
  float* xproj = (float*)ws;                                  // 4 MB
  float* xpart = (float*)(ws + XPROJ_BYTES);                  // nks * 4 MB
  u64*   hmsg  = (u64*)(ws + XPROJ_BYTES * (1 + nks));        // 16 KB
  // hmsg deliberately NOT initialized: 0xAA poison tag never matches [1,256].

  const int kspan = K_IN / nks;
  xproj_gemm<<<dim3(TS / GBN, G4 / GBM, nks), 256, 0, stream>>>(frames, W_ih, xpart, kspan);
  xproj_reduce<<<dim3(TS * G4 / 4 / 256), 256, 0, stream>>>(xpart, nks, b_ih, b_hh, xproj);
  lstm_scan<<<dim3(NWG), 256, 0, stream>>>(W_hh, xproj, hmsg);
  fc_kernel<<<dim3(12288 / 64), 256, 0, stream>>>(fc_w, fc_b, hmsg, out);
}